// Round 1
// baseline (205.079 us; speedup 1.0000x reference)
//
#include <hip/hip_runtime.h>
#include <math.h>

// Problem constants (B=4, S=4096, D=2048, fp32)
#define NBATCH 4
#define SROWS  4096
#define DCOLS  2048
#define BPB    128                              // blocks per batch
#define ROWS_PER_WAVE (SROWS / (BPB * 4))       // = 8

// Kernel 1: for each batch b, accumulate s_b[d] = sum_i h[b,i,d] / max(||h[b,i,:]||, eps)
// Wave-per-row: 64 lanes x 8 float4 segments = 2048 columns.
// Per-lane fp32 partials over ROWS_PER_WAVE rows, block LDS reduce, then one
// double atomicAdd per column per block into the workspace accumulator.
__global__ __launch_bounds__(256, 2)
void row_normalize_sum(const float* __restrict__ h, double* __restrict__ s_acc) {
    const int b    = blockIdx.x >> 7;            // / BPB (BPB == 128)
    const int blk  = blockIdx.x & (BPB - 1);
    const int wave = threadIdx.x >> 6;           // 0..3
    const int lane = threadIdx.x & 63;

    const float* hb = h + (size_t)b * SROWS * DCOLS;
    const int wid      = blk * 4 + wave;         // 0..511 within batch
    const int row_base = wid * ROWS_PER_WAVE;

    float acc[32];
#pragma unroll
    for (int i = 0; i < 32; ++i) acc[i] = 0.0f;

    for (int r = 0; r < ROWS_PER_WAVE; r += 2) {
        const float4* p0 = (const float4*)(hb + (size_t)(row_base + r)     * DCOLS) + lane;
        const float4* p1 = (const float4*)(hb + (size_t)(row_base + r + 1) * DCOLS) + lane;
        float4 v0[8], v1[8];
#pragma unroll
        for (int s = 0; s < 8; ++s) v0[s] = p0[s * 64];
#pragma unroll
        for (int s = 0; s < 8; ++s) v1[s] = p1[s * 64];

        float ss0 = 0.0f, ss1 = 0.0f;
#pragma unroll
        for (int s = 0; s < 8; ++s) {
            ss0 += v0[s].x * v0[s].x + v0[s].y * v0[s].y + v0[s].z * v0[s].z + v0[s].w * v0[s].w;
            ss1 += v1[s].x * v1[s].x + v1[s].y * v1[s].y + v1[s].z * v1[s].z + v1[s].w * v1[s].w;
        }
        // 64-lane butterfly reduction (wave = 64 on CDNA)
#pragma unroll
        for (int m = 32; m >= 1; m >>= 1) {
            ss0 += __shfl_xor(ss0, m, 64);
            ss1 += __shfl_xor(ss1, m, 64);
        }
        // inv = 1 / max(||row||, eps); double sqrt once per row for accuracy
        const float inv0 = (float)(1.0 / fmax(sqrt((double)ss0), 1e-12));
        const float inv1 = (float)(1.0 / fmax(sqrt((double)ss1), 1e-12));
#pragma unroll
        for (int s = 0; s < 8; ++s) {
            acc[s * 4 + 0] += v0[s].x * inv0;
            acc[s * 4 + 1] += v0[s].y * inv0;
            acc[s * 4 + 2] += v0[s].z * inv0;
            acc[s * 4 + 3] += v0[s].w * inv0;
            acc[s * 4 + 0] += v1[s].x * inv1;
            acc[s * 4 + 1] += v1[s].y * inv1;
            acc[s * 4 + 2] += v1[s].z * inv1;
            acc[s * 4 + 3] += v1[s].w * inv1;
        }
    }

    // Block reduction across the 4 waves via LDS (32 KiB), then double atomics.
    __shared__ float red[4][DCOLS];
#pragma unroll
    for (int s = 0; s < 8; ++s) {
        float4* dst = (float4*)&red[wave][s * 256 + lane * 4];
        *dst = make_float4(acc[s * 4 + 0], acc[s * 4 + 1], acc[s * 4 + 2], acc[s * 4 + 3]);
    }
    __syncthreads();

#pragma unroll
    for (int k = 0; k < 8; ++k) {
        const int c = k * 256 + threadIdx.x;
        const double v = (double)red[0][c] + (double)red[1][c]
                       + (double)red[2][c] + (double)red[3][c];
        atomicAdd(&s_acc[(size_t)b * DCOLS + c], v);
    }
}

// Kernel 2: ssq = sum_b ||s_b||^2 (double), then
// conc = (ssq - B*S) / (B*S*(S-1)); lambda = sigmoid(alpha*(conc-beta)).
__global__ void finalize_kernel(const double* __restrict__ s_acc,
                                const float* __restrict__ alpha,
                                const float* __restrict__ beta,
                                float* __restrict__ out) {
    __shared__ double red[256];
    double ssq = 0.0;
    for (int i = threadIdx.x; i < NBATCH * DCOLS; i += 256) {
        const double v = s_acc[i];
        ssq += v * v;
    }
    red[threadIdx.x] = ssq;
    __syncthreads();
    for (int off = 128; off > 0; off >>= 1) {
        if (threadIdx.x < off) red[threadIdx.x] += red[threadIdx.x + off];
        __syncthreads();
    }
    if (threadIdx.x == 0) {
        const double num   = red[0] - (double)NBATCH * (double)SROWS;
        const double denom = (double)NBATCH * (double)SROWS * (double)(SROWS - 1);
        const double conc  = num / denom;
        const double a = (double)alpha[0];
        const double bt = (double)beta[0];
        const double lam = 1.0 / (1.0 + exp(-a * (conc - bt)));
        out[0] = (float)lam;   // lambda_t
        out[1] = (float)conc;  // conc
    }
}

extern "C" void kernel_launch(void* const* d_in, const int* in_sizes, int n_in,
                              void* d_out, int out_size, void* d_ws, size_t ws_size,
                              hipStream_t stream) {
    (void)in_sizes; (void)n_in; (void)out_size; (void)ws_size;
    const float* h     = (const float*)d_in[0];
    const float* alpha = (const float*)d_in[1];
    const float* beta  = (const float*)d_in[2];
    float* out         = (float*)d_out;
    double* s_acc      = (double*)d_ws;   // NBATCH*DCOLS doubles = 64 KiB

    // ws is poisoned (0xAA) before every launch — zero the accumulator.
    hipMemsetAsync(s_acc, 0, (size_t)NBATCH * DCOLS * sizeof(double), stream);

    row_normalize_sum<<<NBATCH * BPB, 256, 0, stream>>>(h, s_acc);
    finalize_kernel<<<1, 256, 0, stream>>>(s_acc, alpha, beta, out);
}

// Round 2
// 199.970 us; speedup vs baseline: 1.0255x; 1.0255x over previous
//
#include <hip/hip_runtime.h>
#include <math.h>

// Problem constants (B=4, S=4096, D=2048, fp32)
#define NBATCH 4
#define SROWS  4096
#define DCOLS  2048
#define BPB    128                              // blocks per batch
#define NBLK1  (NBATCH * BPB)                   // 512
#define ROWS_PER_WAVE (SROWS / (BPB * 4))       // = 8

// Workspace layout:
//   part    : float [NBLK1][DCOLS]   = 4 MiB   (per-block partial column sums)
//   ssq_part: double[64]             (per-block partial sum-of-squares)
#define SSQ_OFFSET ((size_t)NBLK1 * DCOLS)      // in floats

// Kernel 1: per-block partial of s_b[d] = sum_i h[b,i,d] / max(||h[b,i,:]||, eps).
// Wave-per-row: 64 lanes x 8 float4 segments = 2048 columns. fp32 partials over
// 8 rows/wave, LDS reduce across the block's 4 waves, coalesced partial store.
// No atomics, no memset needed (ws fully overwritten before read).
__global__ __launch_bounds__(256, 2)
void row_normalize_sum(const float* __restrict__ h, float* __restrict__ part) {
    const int b    = blockIdx.x >> 7;            // / BPB (BPB == 128)
    const int blk  = blockIdx.x & (BPB - 1);
    const int wave = threadIdx.x >> 6;           // 0..3
    const int lane = threadIdx.x & 63;

    const float* hb = h + (size_t)b * SROWS * DCOLS;
    const int wid      = blk * 4 + wave;         // 0..511 within batch
    const int row_base = wid * ROWS_PER_WAVE;

    float acc[32];
#pragma unroll
    for (int i = 0; i < 32; ++i) acc[i] = 0.0f;

    for (int r = 0; r < ROWS_PER_WAVE; r += 2) {
        const float4* p0 = (const float4*)(hb + (size_t)(row_base + r)     * DCOLS) + lane;
        const float4* p1 = (const float4*)(hb + (size_t)(row_base + r + 1) * DCOLS) + lane;
        float4 v0[8], v1[8];
#pragma unroll
        for (int s = 0; s < 8; ++s) v0[s] = p0[s * 64];
#pragma unroll
        for (int s = 0; s < 8; ++s) v1[s] = p1[s * 64];

        float ss0 = 0.0f, ss1 = 0.0f;
#pragma unroll
        for (int s = 0; s < 8; ++s) {
            ss0 += v0[s].x * v0[s].x + v0[s].y * v0[s].y + v0[s].z * v0[s].z + v0[s].w * v0[s].w;
            ss1 += v1[s].x * v1[s].x + v1[s].y * v1[s].y + v1[s].z * v1[s].z + v1[s].w * v1[s].w;
        }
        // 64-lane butterfly reduction (wave = 64 on CDNA)
#pragma unroll
        for (int m = 32; m >= 1; m >>= 1) {
            ss0 += __shfl_xor(ss0, m, 64);
            ss1 += __shfl_xor(ss1, m, 64);
        }
        // inv = 1 / max(||row||, eps); double sqrt once per row for accuracy
        const float inv0 = (float)(1.0 / fmax(sqrt((double)ss0), 1e-12));
        const float inv1 = (float)(1.0 / fmax(sqrt((double)ss1), 1e-12));
#pragma unroll
        for (int s = 0; s < 8; ++s) {
            acc[s * 4 + 0] += v0[s].x * inv0;
            acc[s * 4 + 1] += v0[s].y * inv0;
            acc[s * 4 + 2] += v0[s].z * inv0;
            acc[s * 4 + 3] += v0[s].w * inv0;
            acc[s * 4 + 0] += v1[s].x * inv1;
            acc[s * 4 + 1] += v1[s].y * inv1;
            acc[s * 4 + 2] += v1[s].z * inv1;
            acc[s * 4 + 3] += v1[s].w * inv1;
        }
    }

    // Block reduction across the 4 waves via LDS (32 KiB), then coalesced store.
    __shared__ float red[4][DCOLS];
#pragma unroll
    for (int s = 0; s < 8; ++s) {
        float4* dst = (float4*)&red[wave][s * 256 + lane * 4];
        *dst = make_float4(acc[s * 4 + 0], acc[s * 4 + 1], acc[s * 4 + 2], acc[s * 4 + 3]);
    }
    __syncthreads();

    float* dst = part + (size_t)blockIdx.x * DCOLS;
#pragma unroll
    for (int k = 0; k < 8; ++k) {
        const int c = k * 256 + threadIdx.x;
        dst[c] = red[0][c] + red[1][c] + red[2][c] + red[3][c];
    }
}

// Kernel 2: 64 blocks. Block k: batch b = k>>4, columns [(k&15)*128, +128).
// Sum the batch's 128 partials per column in double, square, block-reduce,
// write one partial ssq double per block.
__global__ __launch_bounds__(256, 4)
void reduce_partials(const float* __restrict__ part, double* __restrict__ ssq_part) {
    const int b    = blockIdx.x >> 4;
    const int c    = ((blockIdx.x & 15) * 128) + (threadIdx.x & 127);
    const int half = threadIdx.x >> 7;           // 0 or 1
    const float* pb = part + (size_t)b * BPB * DCOLS;

    double sum = 0.0;
    const int p0 = half * 64;
#pragma unroll 8
    for (int p = p0; p < p0 + 64; ++p)
        sum += (double)pb[(size_t)p * DCOLS + c];

    __shared__ double sh[256];
    sh[threadIdx.x] = sum;
    __syncthreads();

    double ssq = 0.0;
    if (threadIdx.x < 128) {
        const double s = sh[threadIdx.x] + sh[threadIdx.x + 128];
        ssq = s * s;
    }
    __syncthreads();
    sh[threadIdx.x] = ssq;
    __syncthreads();
    for (int off = 64; off > 0; off >>= 1) {
        if (threadIdx.x < off) sh[threadIdx.x] += sh[threadIdx.x + off];
        __syncthreads();
    }
    if (threadIdx.x == 0) ssq_part[blockIdx.x] = sh[0];
}

// Kernel 3: one wave. ssq = sum of 64 partials; conc = (ssq - B*S)/(B*S*(S-1));
// lambda = sigmoid(alpha*(conc-beta)).
__global__ void finalize_kernel(const double* __restrict__ ssq_part,
                                const float* __restrict__ alpha,
                                const float* __restrict__ beta,
                                float* __restrict__ out) {
    double v = ssq_part[threadIdx.x];
#pragma unroll
    for (int m = 32; m >= 1; m >>= 1) v += __shfl_xor(v, m, 64);
    if (threadIdx.x == 0) {
        const double num   = v - (double)NBATCH * (double)SROWS;
        const double denom = (double)NBATCH * (double)SROWS * (double)(SROWS - 1);
        const double conc  = num / denom;
        const double a  = (double)alpha[0];
        const double bt = (double)beta[0];
        const double lam = 1.0 / (1.0 + exp(-a * (conc - bt)));
        out[0] = (float)lam;   // lambda_t
        out[1] = (float)conc;  // conc
    }
}

extern "C" void kernel_launch(void* const* d_in, const int* in_sizes, int n_in,
                              void* d_out, int out_size, void* d_ws, size_t ws_size,
                              hipStream_t stream) {
    (void)in_sizes; (void)n_in; (void)out_size; (void)ws_size;
    const float* h     = (const float*)d_in[0];
    const float* alpha = (const float*)d_in[1];
    const float* beta  = (const float*)d_in[2];
    float* out         = (float*)d_out;
    float* part        = (float*)d_ws;                       // 4 MiB partials
    double* ssq_part   = (double*)((float*)d_ws + SSQ_OFFSET); // 64 doubles

    row_normalize_sum<<<NBLK1, 256, 0, stream>>>(h, part);
    reduce_partials<<<64, 256, 0, stream>>>(part, ssq_part);
    finalize_kernel<<<1, 64, 0, stream>>>(ssq_part, alpha, beta, out);
}